// Round 9
// baseline (1156.879 us; speedup 1.0000x reference)
//
#include <hip/hip_runtime.h>
#include <hip/hip_bf16.h>

#define BSZ 4096
#define MAXLEN 200
#define EDIM 112
#define NPL 8   // K-split partial planes (one per kq block)

typedef __attribute__((ext_vector_type(8))) short bf16x8;
typedef __attribute__((ext_vector_type(4))) float f32x4;

// f32 -> bf16 (RNE), bit-level
static __device__ __forceinline__ short f2bf(float f) {
    unsigned u = __float_as_uint(f);
    unsigned r = (u + 0x7fffu + ((u >> 16) & 1u)) >> 16;
    return (short)r;
}
static __device__ __forceinline__ float bf2f(short s) {
    return __uint_as_float(((unsigned)(unsigned short)s) << 16);
}
static __device__ __forceinline__ bf16x8 cvt8(float4 a, float4 b) {
    bf16x8 r;
    r[0] = f2bf(a.x); r[1] = f2bf(a.y); r[2] = f2bf(a.z); r[3] = f2bf(a.w);
    r[4] = f2bf(b.x); r[5] = f2bf(b.y); r[6] = f2bf(b.z); r[7] = f2bf(b.w);
    return r;
}
static __device__ __forceinline__ unsigned pack2(float a, float b) {
    return ((unsigned)f2bf(a) & 0xffffu) | ((unsigned)f2bf(b) << 16);
}

// async global->LDS, 16 B per lane: global src per-lane, LDS dest uniform+lane*16.
static __device__ __forceinline__ void glds16(const unsigned short* g, unsigned short* l) {
    __builtin_amdgcn_global_load_lds(
        (__attribute__((address_space(1))) void*)(void*)g,
        (__attribute__((address_space(3))) void*)l, 16, 0, 0);
}

// Streaming f32 -> bf16; first `zgroups` 8-elem groups are zeros (PAD row).
__global__ __launch_bounds__(256) void f32_to_bf16(const float* __restrict__ src,
                                                   unsigned short* __restrict__ dst,
                                                   int ngroups, int zgroups) {
    int g = blockIdx.x * 256 + threadIdx.x;
    if (g >= ngroups) return;
    bf16x8 o;
    if (g < zgroups) {
        #pragma unroll
        for (int i = 0; i < 8; ++i) o[i] = 0;
    } else {
        const float* p = src + (size_t)(g - zgroups) * 8;
        float4 a = *(const float4*)p;
        float4 b = *(const float4*)(p + 4);
        o = cvt8(a, b);
    }
    *(bf16x8*)(dst + (size_t)g * 8) = o;
}

// Load 8 consecutive f32 (if valid) -> bf16x8 fragment.
static __device__ __forceinline__ bf16x8 ldcvt(const float* p, bool valid) {
    if (valid) {
        float4 a = *(const float4*)(p);
        float4 b = *(const float4*)(p + 4);
        return cvt8(a, b);
    }
    bf16x8 z;
    #pragma unroll
    for (int i = 0; i < 8; ++i) z[i] = 0;
    return z;
}

// bf16-table gather+mean-pool with FUSED mid0 tail.  One block per session;
// writes S and inits acc.  The LAST block of each 16-session group (atomic
// counter, R8-proven fence pattern) additionally computes the T1 = S @ W0^T
// tile for those 16 sessions on wave 0 -> Bsw0 (replaces the fused_mid0
// kernel + one launch boundary).
__global__ __launch_bounds__(256) void gather_pool_bf(const unsigned short* __restrict__ Ebf,
                                                      const int* __restrict__ items,
                                                      const float* __restrict__ slen,
                                                      float* __restrict__ S,
                                                      float* __restrict__ acc,
                                                      const float* __restrict__ W0,
                                                      unsigned short* __restrict__ Bsw0,
                                                      unsigned* __restrict__ cntG) {
    __shared__ float part[16][14][8];
    __shared__ unsigned short Ylds[16][136];
    __shared__ unsigned gflag;
    int wave = threadIdx.x >> 6;
    int lane = threadIdx.x & 63;
    int b = blockIdx.x;
    int rg = lane / 14;   // 0..3 for lanes 0..55
    int c  = lane % 14;
    const int* it = items + (size_t)b * MAXLEN + wave * 50;
    float a[8];
    #pragma unroll
    for (int e = 0; e < 8; ++e) a[e] = 0.f;
    if (lane < 56) {
        #pragma unroll
        for (int t = 0; t < 13; ++t) {
            int j = t * 4 + rg;
            int idx = 0;
            if (j < 50) idx = it[j];               // idx==0 -> zero row (PAD)
            bf16x8 v = *(const bf16x8*)(Ebf + (size_t)idx * EDIM + c * 8);
            #pragma unroll
            for (int e = 0; e < 8; ++e) a[e] += bf2f(v[e]);
        }
        #pragma unroll
        for (int e = 0; e < 8; ++e) part[wave * 4 + rg][c][e] = a[e];
    }
    __syncthreads();
    int tid = threadIdx.x;
    if (tid < EDIM) {
        int cc = tid >> 3, ee = tid & 7;
        float s = 0.f;
        #pragma unroll
        for (int g = 0; g < 16; ++g) s += part[g][cc][ee];
        s /= slen[b];
        S[(size_t)b * EDIM + tid]   = s;
        acc[(size_t)b * EDIM + tid] = s;
    }

    // ---- last-of-16 tail: mid0 for session group b>>4 ----
    __threadfence();
    __syncthreads();
    if (tid == 0)
        gflag = __hip_atomic_fetch_add(&cntG[b >> 4], 1u,
                                       __ATOMIC_ACQ_REL, __HIP_MEMORY_SCOPE_AGENT);
    __syncthreads();
    if (gflag != 15) return;
    __threadfence();   // acquire: other blocks' S stores visible
    if (wave == 0) {
        int gw = b >> 4;
        int j0 = gw * 16;
        int nrow = lane & 15;
        int quad = lane >> 4;
        int ses = j0 + nrow;
        float4 v[7];
        const float4* p = (const float4*)(S + (size_t)ses * EDIM + quad * 28);
        #pragma unroll
        for (int i = 0; i < 7; ++i) v[i] = p[i];
        #pragma unroll
        for (int i = 0; i < 7; ++i) {
            uint2 pk;
            pk.x = pack2(v[i].x, v[i].y);
            pk.y = pack2(v[i].z, v[i].w);
            *(uint2*)&Ylds[nrow][quad * 28 + i * 4] = pk;
        }
        *(uint2*)&Ylds[nrow][112 + quad * 4] = make_uint2(0u, 0u);
        __builtin_amdgcn_s_waitcnt(0);   // ds_write -> ds_read, same wave (R8-proven)
        bf16x8 aF[4];
        #pragma unroll
        for (int k = 0; k < 4; ++k)
            aF[k] = *(bf16x8*)&Ylds[nrow][k * 32 + quad * 8];
        f32x4 accf[7];
        #pragma unroll
        for (int t = 0; t < 7; ++t) accf[t] = (f32x4){0.f, 0.f, 0.f, 0.f};
        #pragma unroll
        for (int t = 0; t < 7; ++t) {
            const float* wr = W0 + (size_t)(16 * t + nrow) * EDIM;
            #pragma unroll
            for (int k = 0; k < 4; ++k) {
                bf16x8 bF = ldcvt(wr + k * 32 + quad * 8, (k < 3) || (quad < 2));
                accf[t] = __builtin_amdgcn_mfma_f32_16x16x32_bf16(aF[k], bF, accf[t], 0, 0, 0);
            }
        }
        int k32f = j0 >> 5;
        int qp = ((j0 >> 4) & 1) * 2 + (quad >> 1);
        int e0 = (quad & 1) * 4;
        #pragma unroll
        for (int t = 0; t < 7; ++t) {
            uint2 pk;
            pk.x = pack2(accf[t][0], accf[t][1]);
            pk.y = pack2(accf[t][2], accf[t][3]);
            *(uint2*)(Bsw0 + ((size_t)(k32f * 7 + t) * 64 + qp * 16 + nrow) * 8 + e0) = pk;
        }
    }
}

// K-split GEMM with FUSED per-layer epilogue tail.
// grid 256 = 32 M-tiles(128 rows) x 8 K-chunks (K=512), 8 waves x 512 thr.
// GEMM body identical to the (passed) round-6 bg_ks: B slice staged to LDS
// in two 28-KB phases; 16 A-frags reg-prefetched; 112 MFMA/wave with no
// global loads/barriers in the compute loops; partials -> Yp plane kq.
// TAIL: the LAST of the 8 kq-blocks for each mtile (atomic counter) sums the
// 8 planes, D-scales, L2-normalizes, updates acc (or writes out), and
// computes T' = Y @ W^T -> BswOut -- one wave per 16 sessions (8 waves =
// 128 rows).  Replaces epi_mid / final_epilogue kernels + boundaries.
// AMODE 0: A read f32, cvt, side-write Asw.  AMODE 1: read Asw.  LAST: out.
template <int AMODE, int LAST>
__global__ __launch_bounds__(512, 2) void bg_ks(const float* __restrict__ Af,
                                                unsigned short* __restrict__ Asw,
                                                const unsigned short* __restrict__ Bsw,
                                                float* __restrict__ Yp,
                                                const float* __restrict__ Dm,
                                                float* __restrict__ accb,
                                                const float* __restrict__ W,
                                                unsigned short* __restrict__ BswOut,
                                                float* __restrict__ out,
                                                unsigned* __restrict__ cnt) {
    __shared__ unsigned short Bl[8 * 7 * 512];   // 57,344 B
    __shared__ unsigned flag;
    int tid = threadIdx.x;
    int w = tid >> 6;                 // 0..7 (= sub-mtile owned by this wave)
    int lane = tid & 63;
    int nrow = lane & 15;
    int quad = lane >> 4;
    int mtile = blockIdx.x & 31;      // 128-row tile
    int kq = blockIdx.x >> 5;         // 0..7
    int M16 = mtile * 8 + w;          // 16-row tile index, 0..255
    int k32b = kq * 16;

    // ---- phase-0 B staging: wave w stages local k32 = w (7 frags) ----
    #pragma unroll
    for (int t = 0; t < 7; ++t)
        glds16(Bsw + (((size_t)(k32b + w) * 7 + t) * 64 + lane) * 8,
               &Bl[(w * 7 + t) * 512]);

    // ---- prefetch ALL 16 A-frags into regs (static indices) ----
    bf16x8 aF[16];
    if (AMODE == 0) {
        #pragma unroll
        for (int k = 0; k < 16; ++k) {
            const float* p = Af + (size_t)(M16 * 16 + nrow) * BSZ
                             + (k32b + k) * 32 + quad * 8;
            float4 a0 = *(const float4*)p;
            float4 a1 = *(const float4*)(p + 4);
            aF[k] = cvt8(a0, a1);
            *(bf16x8*)(Asw + (((size_t)M16 * 128 + k32b + k) * 64 + lane) * 8) = aF[k];
        }
    } else {
        #pragma unroll
        for (int k = 0; k < 16; ++k)
            aF[k] = *(const bf16x8*)(Asw + (((size_t)M16 * 128 + k32b + k) * 64 + lane) * 8);
    }

    f32x4 acc[7];
    #pragma unroll
    for (int t = 0; t < 7; ++t) acc[t] = (f32x4){0.f, 0.f, 0.f, 0.f};

    asm volatile("s_waitcnt vmcnt(0)" ::: "memory");
    __syncthreads();

    // ---- compute phase 0: k = 0..7, no barriers, no global loads ----
    #pragma unroll
    for (int k = 0; k < 8; ++k)
        #pragma unroll
        for (int t = 0; t < 7; ++t) {
            bf16x8 bF = *(bf16x8*)&Bl[(k * 7 + t) * 512 + lane * 8];
            acc[t] = __builtin_amdgcn_mfma_f32_16x16x32_bf16(aF[k], bF, acc[t], 0, 0, 0);
        }

    // ---- phase-1 B staging into the same buffer (WAR-safe: barrier both sides)
    __syncthreads();
    #pragma unroll
    for (int t = 0; t < 7; ++t)
        glds16(Bsw + (((size_t)(k32b + 8 + w) * 7 + t) * 64 + lane) * 8,
               &Bl[(w * 7 + t) * 512]);
    asm volatile("s_waitcnt vmcnt(0)" ::: "memory");
    __syncthreads();

    // ---- compute phase 1: k = 8..15 ----
    #pragma unroll
    for (int k = 0; k < 8; ++k)
        #pragma unroll
        for (int t = 0; t < 7; ++t) {
            bf16x8 bF = *(bf16x8*)&Bl[(k * 7 + t) * 512 + lane * 8];
            acc[t] = __builtin_amdgcn_mfma_f32_16x16x32_bf16(aF[8 + k], bF, acc[t], 0, 0, 0);
        }

    // ---- C/D: (m = quad*4 + r, n = 16t + nrow) -> partial plane kq ----
    float* dst = Yp + (size_t)kq * BSZ * EDIM + (size_t)M16 * 16 * EDIM;
    #pragma unroll
    for (int t = 0; t < 7; ++t)
        #pragma unroll
        for (int r = 0; r < 4; ++r)
            dst[(size_t)(quad * 4 + r) * EDIM + 16 * t + nrow] = acc[t][r];

    // ================= last-of-8 epilogue tail =================
    __threadfence();
    __syncthreads();
    if (tid == 0)
        flag = __hip_atomic_fetch_add(&cnt[mtile], 1u,
                                      __ATOMIC_ACQ_REL, __HIP_MEMORY_SCOPE_AGENT);
    __syncthreads();
    if (flag != 7) return;
    __threadfence();   // acquire: other kq blocks' Yp stores visible

    // wave w handles sessions [mtile*128 + 16w, +16); per-wave LDS region
    unsigned short (*Ylds)[136] = (unsigned short(*)[136])&Bl[w * 2304];
    int j0 = mtile * 128 + w * 16;
    int ses = j0 + nrow;
    float4 v[7];
    #pragma unroll
    for (int i = 0; i < 7; ++i) v[i] = make_float4(0.f, 0.f, 0.f, 0.f);
    #pragma unroll
    for (int pp = 0; pp < NPL; ++pp) {
        const float4* p = (const float4*)(Yp + (size_t)pp * BSZ * EDIM
                                          + (size_t)ses * EDIM + quad * 28);
        #pragma unroll
        for (int i = 0; i < 7; ++i) {
            float4 t = p[i];
            v[i].x += t.x; v[i].y += t.y; v[i].z += t.z; v[i].w += t.w;
        }
    }
    float d = Dm[(size_t)ses * (BSZ + 1)];
    float ss = 0.f;
    #pragma unroll
    for (int i = 0; i < 7; ++i) {
        v[i].x *= d; v[i].y *= d; v[i].z *= d; v[i].w *= d;
        ss += v[i].x * v[i].x + v[i].y * v[i].y + v[i].z * v[i].z + v[i].w * v[i].w;
    }
    ss += __shfl_xor(ss, 16, 64);
    ss += __shfl_xor(ss, 32, 64);
    float rinv = 1.f / fmaxf(sqrtf(ss), 1e-12f);
    if (LAST) {
        #pragma unroll
        for (int i = 0; i < 7; ++i) {
            size_t o = (size_t)ses * EDIM + quad * 28 + i * 4;
            float4 a = *(const float4*)(accb + o);
            float4 r;
            r.x = (a.x + v[i].x * rinv) * 0.25f;
            r.y = (a.y + v[i].y * rinv) * 0.25f;
            r.z = (a.z + v[i].z * rinv) * 0.25f;
            r.w = (a.w + v[i].w * rinv) * 0.25f;
            *(float4*)(out + o) = r;
        }
    } else {
        #pragma unroll
        for (int i = 0; i < 7; ++i) {
            size_t o = (size_t)ses * EDIM + quad * 28 + i * 4;
            float4 a = *(const float4*)(accb + o);
            a.x += v[i].x * rinv; a.y += v[i].y * rinv;
            a.z += v[i].z * rinv; a.w += v[i].w * rinv;
            *(float4*)(accb + o) = a;
            uint2 pk;
            pk.x = pack2(v[i].x, v[i].y);
            pk.y = pack2(v[i].z, v[i].w);
            *(uint2*)&Ylds[nrow][quad * 28 + i * 4] = pk;
        }
        *(uint2*)&Ylds[nrow][112 + quad * 4] = make_uint2(0u, 0u);
        __builtin_amdgcn_s_waitcnt(0);   // ds_write -> ds_read, same wave
        bf16x8 aF2[4];
        #pragma unroll
        for (int k = 0; k < 4; ++k)
            aF2[k] = *(bf16x8*)&Ylds[nrow][k * 32 + quad * 8];
        int k32f = j0 >> 5;
        int qp = ((j0 >> 4) & 1) * 2 + (quad >> 1);
        int e0 = (quad & 1) * 4;
        #pragma unroll
        for (int t = 0; t < 7; ++t) {
            f32x4 c = (f32x4){0.f, 0.f, 0.f, 0.f};
            const float* wr = W + (size_t)(16 * t + nrow) * EDIM;
            #pragma unroll
            for (int k = 0; k < 4; ++k) {
                bf16x8 bW = ldcvt(wr + k * 32 + quad * 8, (k < 3) || (quad < 2));
                c = __builtin_amdgcn_mfma_f32_16x16x32_bf16(aF2[k], bW, c, 0, 0, 0);
            }
            uint2 ck;
            ck.x = pack2(c[0], c[1]);
            ck.y = pack2(c[2], c[3]);
            *(uint2*)(BswOut + ((size_t)(k32f * 7 + t) * 64 + qp * 16 + nrow) * 8 + e0) = ck;
        }
    }
}

extern "C" void kernel_launch(void* const* d_in, const int* in_sizes, int n_in,
                              void* d_out, int out_size, void* d_ws, size_t ws_size,
                              hipStream_t stream) {
    (void)in_sizes; (void)n_in; (void)out_size; (void)ws_size;
    const float* emb   = (const float*)d_in[0];
    const float* Dm    = (const float*)d_in[1];
    const float* A     = (const float*)d_in[2];
    const float* slen  = (const float*)d_in[3];
    const float* Ws    = (const float*)d_in[4];
    const int*   items = (const int*)d_in[5];
    float* out = (float*)d_out;

    // workspace layout (16B-aligned), ~76 MB total
    char* w = (char*)d_ws;
    float* Sa   = (float*)w;                                      // 1835008 B
    float* accb = Sa + BSZ * EDIM;                                // 1835008 B
    float* Yp   = accb + BSZ * EDIM;                              // NPL x 1835008 B
    unsigned short* Bsw0 = (unsigned short*)(Yp + (size_t)NPL * BSZ * EDIM); // 917504 B
    unsigned short* Bsw1 = Bsw0 + (size_t)128 * 7 * 64 * 8;       // 917504 B
    unsigned short* Ebf  = Bsw1 + (size_t)128 * 7 * 64 * 8;       // 22400224 B
    unsigned short* Asw  = Ebf + (size_t)100001 * EDIM;           // 33554432 B
    unsigned* cntG = (unsigned*)(Asw + (size_t)BSZ * BSZ);        // 256 u32
    unsigned* cntL = cntG + 256;                                  // 3 x 32 u32

    // 0. zero the tail-gate counters (graph-legal async memset)
    hipMemsetAsync(cntG, 0, (256 + 96) * sizeof(unsigned), stream);
    // 1. embedding table -> bf16 (zero PAD row prepended)
    f32_to_bf16<<<5470, 256, 0, stream>>>(emb, Ebf, 1400014, 14);
    // 2. gather + mean-pool -> S, acc; last-of-16 tail computes T1 -> Bsw0
    gather_pool_bf<<<BSZ, 256, 0, stream>>>(Ebf, items, slen, Sa, accb,
                                            Ws, Bsw0, cntG);
    // 3-5. three layers; last-of-8 tail does epilogue + next-layer T'
    bg_ks<0, 0><<<256, 512, 0, stream>>>(A, Asw, Bsw0, Yp, Dm, accb,
                                         Ws + (size_t)EDIM * EDIM, Bsw1,
                                         nullptr, cntL);
    bg_ks<1, 0><<<256, 512, 0, stream>>>(nullptr, Asw, Bsw1, Yp, Dm, accb,
                                         Ws + (size_t)2 * EDIM * EDIM, Bsw0,
                                         nullptr, cntL + 32);
    bg_ks<1, 1><<<256, 512, 0, stream>>>(nullptr, Asw, Bsw0, Yp, Dm, accb,
                                         nullptr, nullptr, out, cntL + 64);
}

// Round 10
// 261.990 us; speedup vs baseline: 4.4157x; 4.4157x over previous
//
#include <hip/hip_runtime.h>
#include <hip/hip_bf16.h>

#define BSZ 4096
#define MAXLEN 200
#define EDIM 112
#define NW 8   // waves per bg_fused block (split-K factor)

typedef __attribute__((ext_vector_type(8))) short bf16x8;
typedef __attribute__((ext_vector_type(4))) float f32x4;

// f32 -> bf16 (RNE), bit-level
static __device__ __forceinline__ short f2bf(float f) {
    unsigned u = __float_as_uint(f);
    unsigned r = (u + 0x7fffu + ((u >> 16) & 1u)) >> 16;
    return (short)r;
}
static __device__ __forceinline__ float bf2f(short s) {
    return __uint_as_float(((unsigned)(unsigned short)s) << 16);
}
static __device__ __forceinline__ bf16x8 cvt8(float4 a, float4 b) {
    bf16x8 r;
    r[0] = f2bf(a.x); r[1] = f2bf(a.y); r[2] = f2bf(a.z); r[3] = f2bf(a.w);
    r[4] = f2bf(b.x); r[5] = f2bf(b.y); r[6] = f2bf(b.z); r[7] = f2bf(b.w);
    return r;
}
static __device__ __forceinline__ unsigned pack2(float a, float b) {
    return ((unsigned)f2bf(a) & 0xffffu) | ((unsigned)f2bf(b) << 16);
}

// f32-table gather+mean-pool (no bf16 conversion pass: reads emb directly;
// the 44.8 MB table is L3-resident, and this kernel is latency-bound with
// 4096 blocks of TLP, so 32B/lane instead of 16B/lane is ~free).
// One block per session; 4 waves x 4 rows/wave.  idx==0 -> PAD (zeros);
// else row = emb[(idx-1)*112 ...].  Writes S and inits acc.
__global__ __launch_bounds__(256) void gather_pool_f32(const float* __restrict__ emb,
                                                       const int* __restrict__ items,
                                                       const float* __restrict__ slen,
                                                       float* __restrict__ S,
                                                       float* __restrict__ acc) {
    __shared__ float part[16][14][8];
    int wave = threadIdx.x >> 6;
    int lane = threadIdx.x & 63;
    int b = blockIdx.x;
    int rg = lane / 14;   // 0..3 for lanes 0..55
    int c  = lane % 14;
    const int* it = items + (size_t)b * MAXLEN + wave * 50;
    float a[8];
    #pragma unroll
    for (int e = 0; e < 8; ++e) a[e] = 0.f;
    if (lane < 56) {
        #pragma unroll
        for (int t = 0; t < 13; ++t) {
            int j = t * 4 + rg;
            int idx = (j < 50) ? it[j] : 0;
            if (idx > 0) {
                const float* er = emb + (size_t)(idx - 1) * EDIM + c * 8;
                float4 va = *(const float4*)er;
                float4 vb = *(const float4*)(er + 4);
                a[0] += va.x; a[1] += va.y; a[2] += va.z; a[3] += va.w;
                a[4] += vb.x; a[5] += vb.y; a[6] += vb.z; a[7] += vb.w;
            }
        }
        #pragma unroll
        for (int e = 0; e < 8; ++e) part[wave * 4 + rg][c][e] = a[e];
    }
    __syncthreads();
    int tid = threadIdx.x;
    if (tid < EDIM) {
        int cc = tid >> 3, ee = tid & 7;
        float s = 0.f;
        #pragma unroll
        for (int g = 0; g < 16; ++g) s += part[g][cc][ee];
        s /= slen[b];
        S[(size_t)b * EDIM + tid]   = s;
        acc[(size_t)b * EDIM + tid] = s;
    }
}

// Load 8 consecutive f32 (if valid) -> bf16x8 fragment.
static __device__ __forceinline__ bf16x8 ldcvt(const float* p, bool valid) {
    if (valid) {
        float4 a = *(const float4*)(p);
        float4 b = *(const float4*)(p + 4);
        return cvt8(a, b);
    }
    bf16x8 z;
    #pragma unroll
    for (int i = 0; i < 8; ++i) z[i] = 0;
    return z;
}

// Layer-0 only: T1 = S @ W0^T -> Bsw fragment layout.  One wave per 16
// sessions, grid 256.
__global__ __launch_bounds__(64, 4) void fused_mid0(const float* __restrict__ Sin,
                                                    const float* __restrict__ W,
                                                    unsigned short* __restrict__ Bsw) {
    __shared__ unsigned short Ylds[16][136];  // bank-skewed rows
    int lane = threadIdx.x;
    int gw = blockIdx.x;          // 0..255
    int j0 = gw * 16;
    int nrow = lane & 15;
    int quad = lane >> 4;
    int ses = j0 + nrow;

    float4 v[7];
    const float4* p = (const float4*)(Sin + (size_t)ses * EDIM + quad * 28);
    #pragma unroll
    for (int i = 0; i < 7; ++i) v[i] = p[i];

    #pragma unroll
    for (int i = 0; i < 7; ++i) {
        uint2 pk;
        pk.x = pack2(v[i].x, v[i].y);
        pk.y = pack2(v[i].z, v[i].w);
        *(uint2*)&Ylds[nrow][quad * 28 + i * 4] = pk;
    }
    *(uint2*)&Ylds[nrow][112 + quad * 4] = make_uint2(0u, 0u);
    __syncthreads();

    bf16x8 aF[4];
    #pragma unroll
    for (int k32 = 0; k32 < 4; ++k32)
        aF[k32] = *(bf16x8*)&Ylds[nrow][k32 * 32 + quad * 8];

    f32x4 acc[7];
    #pragma unroll
    for (int t = 0; t < 7; ++t) acc[t] = (f32x4){0.f, 0.f, 0.f, 0.f};
    #pragma unroll
    for (int t = 0; t < 7; ++t) {
        const float* wr = W + (size_t)(16 * t + nrow) * EDIM;
        #pragma unroll
        for (int k32 = 0; k32 < 4; ++k32) {
            bf16x8 bF = ldcvt(wr + k32 * 32 + quad * 8, (k32 < 3) || (quad < 2));
            acc[t] = __builtin_amdgcn_mfma_f32_16x16x32_bf16(aF[k32], bF, acc[t], 0, 0, 0);
        }
    }

    int k32f = j0 >> 5;
    int qp = ((j0 >> 4) & 1) * 2 + (quad >> 1);
    int e0 = (quad & 1) * 4;
    #pragma unroll
    for (int t = 0; t < 7; ++t) {
        uint2 pk;
        pk.x = pack2(acc[t][0], acc[t][1]);
        pk.y = pack2(acc[t][2], acc[t][3]);
        *(uint2*)(Bsw + ((size_t)(k32f * 7 + t) * 64 + qp * 16 + nrow) * 8 + e0) = pk;
    }
}

// Fused per-layer kernel (R1-verbatim, the 253.7-us config): Y = D .* (A @ T)
// over the FULL K in one block (8 waves split K, reduce in LDS), then the
// epilogue (acc += Y/||Y||  or  out = (acc + Y/||Y||)/4) and the next
// layer's B-operand T' = Y @ W^T (7 waves, 4 MFMA each) all in-block.
// grid 256 x 512 thr; one block per 16-row M-tile.
// AMODE 0: read f32 A, cvt in-register, side-write Asw.  AMODE 1: read Asw.
// LAST 1: write out, skip T'.
template <int AMODE, int LAST>
__global__ __launch_bounds__(512, 2) void bg_fused(const float* __restrict__ Af,
                                                   unsigned short* __restrict__ Asw,
                                                   const unsigned short* __restrict__ Bsw,
                                                   const float* __restrict__ Dm,
                                                   float* __restrict__ accb,
                                                   const float* __restrict__ W,
                                                   unsigned short* __restrict__ BswOut,
                                                   float* __restrict__ out) {
    __shared__ float part[NW][16][116];        // 59392 B, stride 116 -> 2-way max
    __shared__ unsigned short Ylds[16][136];   // 4352 B
    int tid = threadIdx.x;
    int w = tid >> 6;
    int lane = tid & 63;
    int nrow = lane & 15;
    int quad = lane >> 4;
    int mtile = blockIdx.x;

    // ---- K-chunk GEMM: wave w covers k32 in [16w, 16w+16) ----
    f32x4 acc[7];
    #pragma unroll
    for (int t = 0; t < 7; ++t) acc[t] = (f32x4){0.f, 0.f, 0.f, 0.f};

    auto LOADA = [&](int k32) -> bf16x8 {
        size_t afrag = ((size_t)(mtile * 128 + k32) * 64 + lane) * 8;
        if (AMODE == 0) {
            const float* p = Af + (size_t)(mtile * 16 + nrow) * 4096 + k32 * 32 + quad * 8;
            float4 a0 = *(const float4*)p;
            float4 a1 = *(const float4*)(p + 4);
            bf16x8 r = cvt8(a0, a1);
            *(bf16x8*)(Asw + afrag) = r;       // side output for layers 2-3
            return r;
        } else {
            return *(const bf16x8*)(Asw + afrag);
        }
    };

    int k32 = w * 16;
    bf16x8 aF = LOADA(k32);
    bf16x8 bF[7];
    {
        const unsigned short* bb = Bsw + ((size_t)k32 * 7 * 64 + lane) * 8;
        #pragma unroll
        for (int t = 0; t < 7; ++t) bF[t] = *(const bf16x8*)(bb + (size_t)t * 512);
    }
    #pragma unroll 1
    for (int ks = 0; ks < 15; ++ks) {
        bf16x8 aN = LOADA(k32 + 1);
        bf16x8 bN[7];
        const unsigned short* bb = Bsw + ((size_t)(k32 + 1) * 7 * 64 + lane) * 8;
        #pragma unroll
        for (int t = 0; t < 7; ++t) bN[t] = *(const bf16x8*)(bb + (size_t)t * 512);
        #pragma unroll
        for (int t = 0; t < 7; ++t)
            acc[t] = __builtin_amdgcn_mfma_f32_16x16x32_bf16(aF, bF[t], acc[t], 0, 0, 0);
        aF = aN;
        #pragma unroll
        for (int t = 0; t < 7; ++t) bF[t] = bN[t];
        ++k32;
    }
    #pragma unroll
    for (int t = 0; t < 7; ++t)
        acc[t] = __builtin_amdgcn_mfma_f32_16x16x32_bf16(aF, bF[t], acc[t], 0, 0, 0);

    // ---- partials to LDS: element (m=quad*4+r, n=16t+nrow) ----
    #pragma unroll
    for (int t = 0; t < 7; ++t)
        #pragma unroll
        for (int r = 0; r < 4; ++r)
            part[w][quad * 4 + r][16 * t + nrow] = acc[t][r];
    __syncthreads();

    // ---- reduce + epilogue: half-wave (32 lanes, 28 active) per row ----
    int half = lane >> 5;
    int cg = lane & 31;           // float4 column group; 28..31 are K-pad
    int row = 2 * w + half;       // 0..15
    int grow = mtile * 16 + row;
    int col = cg * 4;
    float4 v = make_float4(0.f, 0.f, 0.f, 0.f);
    if (cg < 28) {
        #pragma unroll
        for (int p = 0; p < NW; ++p) {
            float4 t = *(const float4*)&part[p][row][col];
            v.x += t.x; v.y += t.y; v.z += t.z; v.w += t.w;
        }
    }
    float d = Dm[(size_t)grow * (BSZ + 1)];   // D diagonal
    v.x *= d; v.y *= d; v.z *= d; v.w *= d;
    float ss = v.x * v.x + v.y * v.y + v.z * v.z + v.w * v.w;
    ss += __shfl_xor(ss, 1, 64);
    ss += __shfl_xor(ss, 2, 64);
    ss += __shfl_xor(ss, 4, 64);
    ss += __shfl_xor(ss, 8, 64);
    ss += __shfl_xor(ss, 16, 64);             // stays within the 32-lane half
    float rinv = 1.f / fmaxf(sqrtf(ss), 1e-12f);
    if (cg < 28) {
        if (LAST) {
            float4 a = *(const float4*)(accb + (size_t)grow * EDIM + col);
            float4 o;
            o.x = (a.x + v.x * rinv) * 0.25f;
            o.y = (a.y + v.y * rinv) * 0.25f;
            o.z = (a.z + v.z * rinv) * 0.25f;
            o.w = (a.w + v.w * rinv) * 0.25f;
            *(float4*)(out + (size_t)grow * EDIM + col) = o;
        } else {
            float4* pa = (float4*)(accb + (size_t)grow * EDIM + col);
            float4 a = *pa;
            a.x += v.x * rinv; a.y += v.y * rinv;
            a.z += v.z * rinv; a.w += v.w * rinv;
            *pa = a;
        }
    }

    if (!LAST) {
        // un-normalized (d-scaled) Y -> bf16 Ylds; cg>=28 writes zeros (K-pad)
        uint2 pk;
        pk.x = pack2(v.x, v.y);
        pk.y = pack2(v.z, v.w);
        *(uint2*)&Ylds[row][col] = pk;
        __syncthreads();

        // ---- T' = Y @ W^T: wave t (<7) does W-tile t: 4 MFMA ----
        if (w < 7) {
            int t = w;
            bf16x8 aF2[4];
            #pragma unroll
            for (int k = 0; k < 4; ++k)
                aF2[k] = *(bf16x8*)&Ylds[nrow][k * 32 + quad * 8];
            f32x4 c = (f32x4){0.f, 0.f, 0.f, 0.f};
            const float* wr = W + (size_t)(16 * t + nrow) * EDIM;
            #pragma unroll
            for (int k = 0; k < 4; ++k) {
                bf16x8 bW = ldcvt(wr + k * 32 + quad * 8, (k < 3) || (quad < 2));
                c = __builtin_amdgcn_mfma_f32_16x16x32_bf16(aF2[k], bW, c, 0, 0, 0);
            }
            int j0 = mtile * 16;
            int k32f = j0 >> 5;
            int qp = ((j0 >> 4) & 1) * 2 + (quad >> 1);
            int e0 = (quad & 1) * 4;
            uint2 ck;
            ck.x = pack2(c[0], c[1]);
            ck.y = pack2(c[2], c[3]);
            *(uint2*)(BswOut + ((size_t)(k32f * 7 + t) * 64 + qp * 16 + nrow) * 8 + e0) = ck;
        }
    }
}

extern "C" void kernel_launch(void* const* d_in, const int* in_sizes, int n_in,
                              void* d_out, int out_size, void* d_ws, size_t ws_size,
                              hipStream_t stream) {
    (void)in_sizes; (void)n_in; (void)out_size; (void)ws_size;
    const float* emb   = (const float*)d_in[0];
    const float* Dm    = (const float*)d_in[1];
    const float* A     = (const float*)d_in[2];
    const float* slen  = (const float*)d_in[3];
    const float* Ws    = (const float*)d_in[4];
    const int*   items = (const int*)d_in[5];
    float* out = (float*)d_out;

    // workspace layout (16B-aligned), ~39 MB total (Ebf deleted)
    char* w = (char*)d_ws;
    float* Sa   = (float*)w;                                      // 1835008 B
    float* accb = Sa + BSZ * EDIM;                                // 1835008 B
    unsigned short* Bsw0 = (unsigned short*)(accb + BSZ * EDIM);  // 917504 B
    unsigned short* Bsw1 = Bsw0 + (size_t)128 * 7 * 64 * 8;       // 917504 B
    unsigned short* Asw  = Bsw1 + (size_t)128 * 7 * 64 * 8;       // 33554432 B

    // 1. gather + mean-pool straight from the f32 table -> S, acc
    gather_pool_f32<<<BSZ, 256, 0, stream>>>(emb, items, slen, Sa, accb);
    // 2. T1 = S @ W0^T
    fused_mid0<<<256, 64, 0, stream>>>(Sa, Ws, Bsw0);
    // 3-5. three fused layers (last writes out)
    bg_fused<0, 0><<<256, 512, 0, stream>>>(A, Asw, Bsw0, Dm, accb,
                                            Ws + (size_t)EDIM * EDIM, Bsw1, nullptr);
    bg_fused<1, 0><<<256, 512, 0, stream>>>(nullptr, Asw, Bsw1, Dm, accb,
                                            Ws + (size_t)2 * EDIM * EDIM, Bsw0, nullptr);
    bg_fused<1, 1><<<256, 512, 0, stream>>>(nullptr, Asw, Bsw0, Dm, accb,
                                            nullptr, nullptr, out);
}